// Round 1
// baseline (1435.755 us; speedup 1.0000x reference)
//
#include <hip/hip_runtime.h>
#include <hip/hip_bf16.h>
#include <stdint.h>

#define NB 16
#define NP 4096
#define NSP 1024      // npoint
#define KNN 32        // nsample
#define PTOT (NB*NSP*KNN)      // 524288 rows
#define NTILES (PTOT/16)       // 32768 M-tiles

typedef __attribute__((ext_vector_type(8))) short short8;
typedef __attribute__((ext_vector_type(4))) float f32x4;

__device__ __forceinline__ float fadd_(float a,float b){return __fadd_rn(a,b);}
__device__ __forceinline__ float fmul_(float a,float b){return __fmul_rn(a,b);}
__device__ __forceinline__ float fsub_(float a,float b){return __fsub_rn(a,b);}

__device__ __forceinline__ float bf2f(unsigned short u){
    unsigned int x = ((unsigned int)u) << 16; float f; __builtin_memcpy(&f,&x,4); return f;
}
__device__ __forceinline__ unsigned short f2bf(float f){
    unsigned int x; __builtin_memcpy(&x,&f,4);
    x = x + 0x7fffu + ((x>>16)&1u);
    return (unsigned short)(x>>16);
}

// ---------------------------------------------------------------- FPS
// One block per batch. 256 threads, 16 points/lane in VGPRs.
// Replicates: dist = ((dx*dx + dy*dy) + dz*dz), distance=min, argmax(first-max).
__global__ __launch_bounds__(256,1) void fps_kernel(const float* __restrict__ xyz,
    int* __restrict__ fps_idx, float* __restrict__ new_xyz, float* __restrict__ out0)
{
    const int b = blockIdx.x, tid = threadIdx.x;
    const float* xb = xyz + (size_t)b*3*NP;
    __shared__ float sx[NP], sy[NP], sz[NP];
    __shared__ float swd[4]; __shared__ int swi[4]; __shared__ int s_far;
    float px[16],py[16],pz[16],pd[16];
    const int base = tid*16;
#pragma unroll
    for (int j=0;j<16;j+=4){
        float4 vx = *(const float4*)(xb + base + j);
        float4 vy = *(const float4*)(xb + NP + base + j);
        float4 vz = *(const float4*)(xb + 2*NP + base + j);
        px[j]=vx.x; px[j+1]=vx.y; px[j+2]=vx.z; px[j+3]=vx.w;
        py[j]=vy.x; py[j+1]=vy.y; py[j+2]=vy.z; py[j+3]=vy.w;
        pz[j]=vz.x; pz[j+1]=vz.y; pz[j+2]=vz.z; pz[j+3]=vz.w;
        *(float4*)(sx+base+j)=vx; *(float4*)(sy+base+j)=vy; *(float4*)(sz+base+j)=vz;
        pd[j]=1e10f; pd[j+1]=1e10f; pd[j+2]=1e10f; pd[j+3]=1e10f;
    }
    __syncthreads();
    int far = 0;
    for (int s=0;s<NSP;s++){
        float cx=sx[far], cy=sy[far], cz=sz[far];
        if (tid==0){
            fps_idx[b*NSP+s]=far;
            float* nz = new_xyz + ((size_t)b*NSP+s)*3;
            nz[0]=cx; nz[1]=cy; nz[2]=cz;
            out0[(size_t)b*3*NSP + s]         = cx;
            out0[(size_t)b*3*NSP + NSP + s]   = cy;
            out0[(size_t)b*3*NSP + 2*NSP + s] = cz;
        }
        float bd=-1.0f; int bi=0;
#pragma unroll
        for (int j=0;j<16;j++){
            float dx=fsub_(px[j],cx), dy=fsub_(py[j],cy), dz=fsub_(pz[j],cz);
            float d = fadd_(fadd_(fmul_(dx,dx),fmul_(dy,dy)),fmul_(dz,dz));
            float nd = fminf(pd[j], d); pd[j]=nd;
            if (nd > bd){ bd=nd; bi=base+j; }
        }
#pragma unroll
        for (int off=32; off>0; off>>=1){
            float od = __shfl_down(bd, off, 64);
            int   oi = __shfl_down(bi, off, 64);
            if (od > bd || (od == bd && oi < bi)){ bd=od; bi=oi; }
        }
        if ((tid&63)==0){ swd[tid>>6]=bd; swi[tid>>6]=bi; }
        __syncthreads();
        if (tid==0){
            float fb=swd[0]; int fi=swi[0];
#pragma unroll
            for (int w=1;w<4;w++){
                if (swd[w]>fb || (swd[w]==fb && swi[w]<fi)){ fb=swd[w]; fi=swi[w]; }
            }
            s_far = fi;
        }
        __syncthreads();
        far = s_far;
    }
}

// ---------------------------------------------------------------- ball query + gather
// One wave per center. Ascending-index scan with ballot compaction, first 32 with d<=R2.
// Replicates d = ((-2*dot) + src2) + dst2 expression order.
__global__ __launch_bounds__(256,1) void ball_gather_kernel(const float* __restrict__ xyz,
    const float* __restrict__ pts, const float* __restrict__ new_xyz,
    unsigned short* __restrict__ feat)
{
    const int lane = threadIdx.x & 63, wv = threadIdx.x >> 6;
    const int center = blockIdx.x*4 + wv;
    const int b = center >> 10;
    const float* xb = xyz + (size_t)b*3*NP;
    const float* pb = pts + (size_t)b*6*NP;
    const float* nz = new_xyz + (size_t)center*3;
    const float cx=nz[0], cy=nz[1], cz=nz[2];
    const float src2 = fadd_(fadd_(fmul_(cx,cx),fmul_(cy,cy)),fmul_(cz,cz));
    const float R2 = (float)(0.4*0.4);   // must round via double: 0.4f*0.4f is a different float!
    __shared__ int slots[4][32];
    int total = 0;
    for (int c0=0;c0<NP;c0+=64){
        const int i = c0 + lane;
        float x=xb[i], y=xb[NP+i], z=xb[2*NP+i];
        float dot  = fadd_(fadd_(fmul_(cx,x),fmul_(cy,y)),fmul_(cz,z));
        float dst2 = fadd_(fadd_(fmul_(x,x),fmul_(y,y)),fmul_(z,z));
        float d = fadd_(fadd_(fmul_(-2.0f,dot), src2), dst2);
        bool pred = !(d > R2);
        unsigned long long m = __ballot(pred);
        int pos = total + (int)__popcll(m & ((1ull<<lane)-1ull));
        if (pred && pos < 32) slots[wv][pos] = i;
        total += (int)__popcll(m);
        if (total >= 32) break;
    }
    const int nvalid = total < 32 ? total : 32;
    __syncthreads();
    const int n = lane & 31;
    const int idx = slots[wv][ (n < nvalid) ? n : 0 ];
    unsigned short* fr = feat + (size_t)center*KNN*32 + (size_t)n*32;
    if (lane < 32){
        float gx = fsub_(xb[idx], cx), gy = fsub_(xb[NP+idx], cy), gz = fsub_(xb[2*NP+idx], cz);
        float p0=pb[idx], p1=pb[NP+idx], p2=pb[2*NP+idx], p3=pb[3*NP+idx], p4=pb[4*NP+idx];
        short8 v;
        v[0]=(short)f2bf(gx); v[1]=(short)f2bf(gy); v[2]=(short)f2bf(gz);
        v[3]=(short)f2bf(p0); v[4]=(short)f2bf(p1); v[5]=(short)f2bf(p2);
        v[6]=(short)f2bf(p3); v[7]=(short)f2bf(p4);
        *(short8*)fr = v;
    } else {
        float p5 = pb[5*NP+idx];
        short8 v = (short8){0,0,0,0,0,0,0,0};
        v[0]=(short)f2bf(p5);
        *(short8*)(fr+8)  = v;
        short8 z8 = (short8){0,0,0,0,0,0,0,0};
        *(short8*)(fr+16) = z8;
        *(short8*)(fr+24) = z8;
    }
}

// ---------------------------------------------------------------- conv + stats (MFMA)
// h = in@W^T + bias. Optional input normalization relu(x*A+B) fused in prologue.
// Per-channel sum/sumsq accumulated to stats[slot][2][128] (double).
template<int KT,int OT,bool NORM_IN,bool STORE_H>
__global__ __launch_bounds__(256,1) void conv_kernel(const unsigned short* __restrict__ in,
    const unsigned short* __restrict__ wp, const float* __restrict__ bias,
    const float* __restrict__ nAB, unsigned short* __restrict__ h_out,
    double* __restrict__ stats)
{
    constexpr int K = KT*32, O = OT*16;
    const int lane = threadIdx.x & 63, wv = threadIdx.x >> 6;
    const int col = lane & 15, quad = lane >> 4;
    short8 bf[OT][KT];
#pragma unroll
    for (int t=0;t<OT;t++)
#pragma unroll
        for (int kt=0;kt<KT;kt++)
            bf[t][kt] = *(const short8*)(wp + (size_t)(t*16+col)*K + kt*32 + quad*8);
    float brow[OT];
#pragma unroll
    for (int t=0;t<OT;t++) brow[t] = bias[t*16+col];
    float nA[KT*8], nB[KT*8];
    if constexpr (NORM_IN){
#pragma unroll
        for (int kt=0;kt<KT;kt++)
#pragma unroll
            for (int j=0;j<8;j++){
                int c = kt*32+quad*8+j;
                nA[kt*8+j]=nAB[c]; nB[kt*8+j]=nAB[128+c];
            }
    }
    float ssum[OT], ssq[OT];
#pragma unroll
    for (int t=0;t<OT;t++){ ssum[t]=0.f; ssq[t]=0.f; }
    const int gw = blockIdx.x*4 + wv, nw = gridDim.x*4;
    for (int tile=gw; tile<NTILES; tile+=nw){
        const int row0 = tile*16;
        short8 af[KT];
#pragma unroll
        for (int kt=0;kt<KT;kt++){
            af[kt] = *(const short8*)(in + (size_t)(row0+col)*K + kt*32 + quad*8);
            if constexpr (NORM_IN){
#pragma unroll
                for (int j=0;j<8;j++){
                    float x = bf2f((unsigned short)af[kt][j]);
                    x = fmaxf(x*nA[kt*8+j]+nB[kt*8+j], 0.f);
                    af[kt][j] = (short)f2bf(x);
                }
            }
        }
        f32x4 acc[OT];
#pragma unroll
        for (int t=0;t<OT;t++) acc[t] = (f32x4){0.f,0.f,0.f,0.f};
#pragma unroll
        for (int kt=0;kt<KT;kt++)
#pragma unroll
            for (int t=0;t<OT;t++)
                acc[t] = __builtin_amdgcn_mfma_f32_16x16x32_bf16(af[kt], bf[t][kt], acc[t], 0,0,0);
#pragma unroll
        for (int t=0;t<OT;t++){
#pragma unroll
            for (int r=0;r<4;r++){
                float h = acc[t][r] + brow[t];
                if constexpr (STORE_H)
                    h_out[(size_t)(row0 + quad*4 + r)*O + t*16 + col] = f2bf(h);
                ssum[t] += h; ssq[t] = fmaf(h,h,ssq[t]);
            }
        }
    }
    __shared__ float bsum[128], bssq[128];
    for (int i=threadIdx.x;i<128;i+=256){ bsum[i]=0.f; bssq[i]=0.f; }
    __syncthreads();
#pragma unroll
    for (int t=0;t<OT;t++){
        float v = ssum[t]; v += __shfl_xor(v,16,64); v += __shfl_xor(v,32,64);
        float q = ssq[t];  q += __shfl_xor(q,16,64); q += __shfl_xor(q,32,64);
        if (quad==0){ atomicAdd(&bsum[t*16+col], v); atomicAdd(&bssq[t*16+col], q); }
    }
    __syncthreads();
    if ((int)threadIdx.x < O){
        const int slot = blockIdx.x & 7;
        atomicAdd(&stats[(size_t)(slot*2+0)*128 + threadIdx.x], (double)bsum[threadIdx.x]);
        atomicAdd(&stats[(size_t)(slot*2+1)*128 + threadIdx.x], (double)bssq[threadIdx.x]);
    }
}

// ---------------------------------------------------------------- stats -> (A, B) per channel
__global__ void finalize_kernel(const double* __restrict__ stats, const float* __restrict__ g,
    const float* __restrict__ beta, float* __restrict__ AB, int O)
{
    int o = threadIdx.x;
    if (o >= O) return;
    double s=0.0, q=0.0;
#pragma unroll
    for (int slot=0;slot<8;slot++){
        s += stats[(size_t)(slot*2+0)*128+o];
        q += stats[(size_t)(slot*2+1)*128+o];
    }
    const double cnt = (double)PTOT;
    float mean = (float)(s/cnt);
    float var  = (float)(q/cnt - (s/cnt)*(s/cnt));
    float inv  = rsqrtf(var + 1e-5f);
    float A = g[o]*inv;
    AB[o] = A; AB[128+o] = beta[o] - mean*A;
}

// ---------------------------------------------------------------- layer2 recompute + norm + relu + maxpool
__global__ __launch_bounds__(256,1) void conv_final_kernel(const unsigned short* __restrict__ in,
    const unsigned short* __restrict__ wp, const float* __restrict__ bias,
    const float* __restrict__ nABin, const float* __restrict__ nABout,
    float* __restrict__ out1)
{
    constexpr int KT=2, OT=8, K=64;
    const int lane = threadIdx.x & 63, wv = threadIdx.x >> 6;
    const int col = lane & 15, quad = lane >> 4;
    short8 bf[OT][KT];
#pragma unroll
    for (int t=0;t<OT;t++)
#pragma unroll
        for (int kt=0;kt<KT;kt++)
            bf[t][kt] = *(const short8*)(wp + (size_t)(t*16+col)*K + kt*32 + quad*8);
    float brow[OT], oA[OT], oB[OT];
#pragma unroll
    for (int t=0;t<OT;t++){
        brow[t] = bias[t*16+col];
        oA[t] = nABout[t*16+col];
        oB[t] = nABout[128+t*16+col];
    }
    float nA[16], nB[16];
#pragma unroll
    for (int kt=0;kt<2;kt++)
#pragma unroll
        for (int j=0;j<8;j++){
            int c = kt*32+quad*8+j;
            nA[kt*8+j]=nABin[c]; nB[kt*8+j]=nABin[128+c];
        }
    const int gw = blockIdx.x*4 + wv, nw = gridDim.x*4;
    for (int grp=gw; grp<NB*NSP; grp+=nw){
        float vmax[OT];
#pragma unroll
        for (int t=0;t<OT;t++) vmax[t]=0.f;
#pragma unroll
        for (int mt=0; mt<2; mt++){
            const int row0 = grp*32 + mt*16;
            short8 af[KT];
#pragma unroll
            for (int kt=0;kt<2;kt++){
                af[kt] = *(const short8*)(in + (size_t)(row0+col)*K + kt*32 + quad*8);
#pragma unroll
                for (int j=0;j<8;j++){
                    float x = bf2f((unsigned short)af[kt][j]);
                    x = fmaxf(x*nA[kt*8+j]+nB[kt*8+j], 0.f);
                    af[kt][j] = (short)f2bf(x);
                }
            }
            f32x4 acc[OT];
#pragma unroll
            for (int t=0;t<OT;t++) acc[t] = (f32x4){0.f,0.f,0.f,0.f};
#pragma unroll
            for (int kt=0;kt<2;kt++)
#pragma unroll
                for (int t=0;t<OT;t++)
                    acc[t] = __builtin_amdgcn_mfma_f32_16x16x32_bf16(af[kt], bf[t][kt], acc[t], 0,0,0);
#pragma unroll
            for (int t=0;t<OT;t++){
#pragma unroll
                for (int r=0;r<4;r++){
                    float h = acc[t][r] + brow[t];
                    float x = fmaxf(h*oA[t]+oB[t], 0.f);
                    vmax[t] = fmaxf(vmax[t], x);
                }
            }
        }
#pragma unroll
        for (int t=0;t<OT;t++){
            float v = vmax[t];
            v = fmaxf(v, __shfl_xor(v,16,64));
            v = fmaxf(v, __shfl_xor(v,32,64));
            if (quad==0){
                int o = t*16+col, bb = grp>>10, ss = grp&1023;
                out1[((size_t)bb*128+o)*NSP + ss] = v;
            }
        }
    }
}

// ---------------------------------------------------------------- weight prep (f32 -> bf16, pad K)
__global__ void prep_kernel(const float* __restrict__ w0, const float* __restrict__ w1,
    const float* __restrict__ w2, unsigned short* __restrict__ wp0,
    unsigned short* __restrict__ wp1, unsigned short* __restrict__ wp2)
{
    int t = blockIdx.x*256 + threadIdx.x;
    if (t < 64*32){ int o=t>>5, c=t&31; wp0[t] = (c<9) ? f2bf(w0[o*9+c]) : (unsigned short)0; }
    if (t < 64*64)  wp1[t] = f2bf(w1[t]);
    if (t < 128*64) wp2[t] = f2bf(w2[t]);
}

extern "C" void kernel_launch(void* const* d_in, const int* in_sizes, int n_in,
                              void* d_out, int out_size, void* d_ws, size_t ws_size,
                              hipStream_t stream)
{
    (void)in_sizes; (void)n_in; (void)out_size; (void)ws_size;
    const float* xyz = (const float*)d_in[0];
    const float* pts = (const float*)d_in[1];
    const float* w0  = (const float*)d_in[2];
    const float* b0  = (const float*)d_in[3];
    const float* g0  = (const float*)d_in[4];
    const float* be0 = (const float*)d_in[5];
    const float* w1  = (const float*)d_in[6];
    const float* b1  = (const float*)d_in[7];
    const float* g1  = (const float*)d_in[8];
    const float* be1 = (const float*)d_in[9];
    const float* w2  = (const float*)d_in[10];
    const float* b2  = (const float*)d_in[11];
    const float* g2  = (const float*)d_in[12];
    const float* be2 = (const float*)d_in[13];

    char* ws = (char*)d_ws;
    size_t off = 0;
    auto alloc = [&](size_t sz)->char*{ char* p = ws + off; off = (off + sz + 255) & ~(size_t)255; return p; };
    int*            fps_idx = (int*)           alloc((size_t)NB*NSP*4);
    float*          new_xyz = (float*)         alloc((size_t)NB*NSP*3*4);
    unsigned short* wp0     = (unsigned short*)alloc(64*32*2);
    unsigned short* wp1     = (unsigned short*)alloc(64*64*2);
    unsigned short* wp2     = (unsigned short*)alloc(128*64*2);
    double*         stats   = (double*)        alloc((size_t)3*8*2*128*8);
    float*          AB0     = (float*)         alloc(256*4);
    float*          AB1     = (float*)         alloc(256*4);
    float*          AB2     = (float*)         alloc(256*4);
    unsigned short* feat    = (unsigned short*)alloc((size_t)PTOT*32*2);
    unsigned short* h0      = (unsigned short*)alloc((size_t)PTOT*64*2);
    unsigned short* h1      = (unsigned short*)alloc((size_t)PTOT*64*2);

    float* out0 = (float*)d_out;
    float* out1 = out0 + (size_t)NB*3*NSP;

    hipMemsetAsync(stats, 0, (size_t)3*8*2*128*8, stream);
    prep_kernel<<<32,256,0,stream>>>(w0,w1,w2,wp0,wp1,wp2);
    fps_kernel<<<NB,256,0,stream>>>(xyz, fps_idx, new_xyz, out0);
    ball_gather_kernel<<<NB*NSP/4,256,0,stream>>>(xyz, pts, new_xyz, feat);
    conv_kernel<1,4,false,true><<<1024,256,0,stream>>>(feat, wp0, b0, nullptr, h0, stats);
    finalize_kernel<<<1,128,0,stream>>>(stats, g0, be0, AB0, 64);
    conv_kernel<2,4,true,true><<<1024,256,0,stream>>>(h0, wp1, b1, AB0, h1, stats + 2048);
    finalize_kernel<<<1,128,0,stream>>>(stats + 2048, g1, be1, AB1, 64);
    conv_kernel<2,8,true,false><<<1024,256,0,stream>>>(h1, wp2, b2, AB1, nullptr, stats + 4096);
    finalize_kernel<<<1,128,0,stream>>>(stats + 4096, g2, be2, AB2, 128);
    conv_final_kernel<<<2048,256,0,stream>>>(h1, wp2, b2, AB1, AB2, out1);
}

// Round 2
// 929.692 us; speedup vs baseline: 1.5443x; 1.5443x over previous
//
#include <hip/hip_runtime.h>
#include <hip/hip_bf16.h>
#include <stdint.h>

#define NB 16
#define NP 4096
#define NSP 1024      // npoint
#define KNN 32        // nsample
#define PTOT (NB*NSP*KNN)      // 524288 rows
#define NTILES (PTOT/16)       // 32768 M-tiles

typedef __attribute__((ext_vector_type(8))) short short8;
typedef __attribute__((ext_vector_type(4))) float f32x4;

__device__ __forceinline__ float fadd_(float a,float b){return __fadd_rn(a,b);}
__device__ __forceinline__ float fmul_(float a,float b){return __fmul_rn(a,b);}
__device__ __forceinline__ float fsub_(float a,float b){return __fsub_rn(a,b);}

__device__ __forceinline__ float bf2f(unsigned short u){
    unsigned int x = ((unsigned int)u) << 16; float f; __builtin_memcpy(&f,&x,4); return f;
}
__device__ __forceinline__ unsigned short f2bf(float f){
    unsigned int x; __builtin_memcpy(&x,&f,4);
    x = x + 0x7fffu + ((x>>16)&1u);
    return (unsigned short)(x>>16);
}

// u64 packed max step via DPP (both halves), identity 0 for invalid lanes.
template<int CTRL>
__device__ __forceinline__ unsigned long long dpp_max_step(unsigned long long v){
    unsigned int lo = (unsigned int)v, hi = (unsigned int)(v>>32);
    unsigned int lod = (unsigned int)__builtin_amdgcn_update_dpp(0, (int)lo, CTRL, 0xF, 0xF, true);
    unsigned int hid = (unsigned int)__builtin_amdgcn_update_dpp(0, (int)hi, CTRL, 0xF, 0xF, true);
    unsigned long long o = ((unsigned long long)hid<<32) | lod;
    return (o > v) ? o : v;
}

// ---------------------------------------------------------------- FPS v2
// One block per batch, 512 threads (8 waves), 8 points/lane in VGPRs.
// Packed (dist,4095-idx) u64 argmax: DPP wave reduce + single-barrier
// cross-wave reduce via ping-pong LDS slots. No global traffic in loop.
// Replicates: dist = ((dx*dx + dy*dy) + dz*dz), distance=min, argmax first-max.
__global__ __launch_bounds__(512,1) void fps_kernel(const float* __restrict__ xyz,
    int* __restrict__ fps_idx)
{
    const int b = blockIdx.x, tid = threadIdx.x;
    const int lane = tid & 63, wv = tid >> 6;
    const float* xb = xyz + (size_t)b*3*NP;
    __shared__ float4 sp[NP];                       // 64 KB, (x,y,z,0)
    __shared__ unsigned long long slots[2][8];
    __shared__ int farr[NSP];
    float px[8],py[8],pz[8],pd[8];
    const int base = tid*8;
#pragma unroll
    for (int j=0;j<8;j+=4){
        float4 vx = *(const float4*)(xb + base + j);
        float4 vy = *(const float4*)(xb + NP + base + j);
        float4 vz = *(const float4*)(xb + 2*NP + base + j);
        px[j]=vx.x; px[j+1]=vx.y; px[j+2]=vx.z; px[j+3]=vx.w;
        py[j]=vy.x; py[j+1]=vy.y; py[j+2]=vy.z; py[j+3]=vy.w;
        pz[j]=vz.x; pz[j+1]=vz.y; pz[j+2]=vz.z; pz[j+3]=vz.w;
        sp[base+j+0] = make_float4(vx.x,vy.x,vz.x,0.f);
        sp[base+j+1] = make_float4(vx.y,vy.y,vz.y,0.f);
        sp[base+j+2] = make_float4(vx.z,vy.z,vz.z,0.f);
        sp[base+j+3] = make_float4(vx.w,vy.w,vz.w,0.f);
        pd[j]=1e10f; pd[j+1]=1e10f; pd[j+2]=1e10f; pd[j+3]=1e10f;
    }
    __syncthreads();
    int far = 0;
    float cx, cy, cz;
    { float4 c0 = sp[0]; cx=c0.x; cy=c0.y; cz=c0.z; }
    for (int s=0;s<NSP;s++){
        if (tid==0) farr[s]=far;
        float bd=-1.0f; int bi=0;
#pragma unroll
        for (int j=0;j<8;j++){
            float dx=fsub_(px[j],cx), dy=fsub_(py[j],cy), dz=fsub_(pz[j],cz);
            float d = fadd_(fadd_(fmul_(dx,dx),fmul_(dy,dy)),fmul_(dz,dz));
            float nd = fminf(pd[j], d); pd[j]=nd;
            if (nd > bd){ bd=nd; bi=base+j; }   // strict > keeps smallest idx on tie
        }
        unsigned int hb; __builtin_memcpy(&hb,&bd,4);
        unsigned long long best = ((unsigned long long)hb<<32) | (unsigned int)(NP-1-bi);
        best = dpp_max_step<0x111>(best);   // row_shr:1
        best = dpp_max_step<0x112>(best);   // row_shr:2
        best = dpp_max_step<0x114>(best);   // row_shr:4
        best = dpp_max_step<0x118>(best);   // row_shr:8
        best = dpp_max_step<0x142>(best);   // row_bcast:15
        best = dpp_max_step<0x143>(best);   // row_bcast:31  -> lane 63 has wave max
        if (lane==63) slots[s&1][wv] = best;
        __syncthreads();
        unsigned long long m = slots[s&1][0];
#pragma unroll
        for (int w=1;w<8;w++){ unsigned long long v = slots[s&1][w]; if (v > m) m = v; }
        far = NP-1-(int)(m & 0xFFFFFFFFu);
        float4 c = sp[far]; cx=c.x; cy=c.y; cz=c.z;
    }
    __syncthreads();
    for (int i=tid;i<NSP;i+=512) fps_idx[b*NSP+i] = farr[i];
}

// ---------------------------------------------------------------- centroids from fps_idx
__global__ void centroid_kernel(const float* __restrict__ xyz, const int* __restrict__ fps_idx,
    float* __restrict__ new_xyz, float* __restrict__ out0)
{
    int t = blockIdx.x*256 + threadIdx.x;
    if (t >= NB*NSP) return;
    int b = t>>10, s = t&1023;
    int id = fps_idx[t];
    const float* xb = xyz + (size_t)b*3*NP;
    float x=xb[id], y=xb[NP+id], z=xb[2*NP+id];
    float* nz = new_xyz + (size_t)t*3;
    nz[0]=x; nz[1]=y; nz[2]=z;
    out0[(size_t)b*3*NSP + s]         = x;
    out0[(size_t)b*3*NSP + NSP + s]   = y;
    out0[(size_t)b*3*NSP + 2*NSP + s] = z;
}

// ---------------------------------------------------------------- ball query + gather
// One wave per center. Ascending-index scan with ballot compaction, first 32 with d<=R2.
// Replicates d = ((-2*dot) + src2) + dst2 expression order.
__global__ __launch_bounds__(256,1) void ball_gather_kernel(const float* __restrict__ xyz,
    const float* __restrict__ pts, const float* __restrict__ new_xyz,
    unsigned short* __restrict__ feat)
{
    const int lane = threadIdx.x & 63, wv = threadIdx.x >> 6;
    const int center = blockIdx.x*4 + wv;
    const int b = center >> 10;
    const float* xb = xyz + (size_t)b*3*NP;
    const float* pb = pts + (size_t)b*6*NP;
    const float* nz = new_xyz + (size_t)center*3;
    const float cx=nz[0], cy=nz[1], cz=nz[2];
    const float src2 = fadd_(fadd_(fmul_(cx,cx),fmul_(cy,cy)),fmul_(cz,cz));
    const float R2 = (float)(0.4*0.4);   // must round via double: 0.4f*0.4f is a different float!
    __shared__ int slots[4][32];
    int total = 0;
    for (int c0=0;c0<NP;c0+=64){
        const int i = c0 + lane;
        float x=xb[i], y=xb[NP+i], z=xb[2*NP+i];
        float dot  = fadd_(fadd_(fmul_(cx,x),fmul_(cy,y)),fmul_(cz,z));
        float dst2 = fadd_(fadd_(fmul_(x,x),fmul_(y,y)),fmul_(z,z));
        float d = fadd_(fadd_(fmul_(-2.0f,dot), src2), dst2);
        bool pred = !(d > R2);
        unsigned long long m = __ballot(pred);
        int pos = total + (int)__popcll(m & ((1ull<<lane)-1ull));
        if (pred && pos < 32) slots[wv][pos] = i;
        total += (int)__popcll(m);
        if (total >= 32) break;
    }
    const int nvalid = total < 32 ? total : 32;
    __syncthreads();
    const int n = lane & 31;
    const int idx = slots[wv][ (n < nvalid) ? n : 0 ];
    unsigned short* fr = feat + (size_t)center*KNN*32 + (size_t)n*32;
    if (lane < 32){
        float gx = fsub_(xb[idx], cx), gy = fsub_(xb[NP+idx], cy), gz = fsub_(xb[2*NP+idx], cz);
        float p0=pb[idx], p1=pb[NP+idx], p2=pb[2*NP+idx], p3=pb[3*NP+idx], p4=pb[4*NP+idx];
        short8 v;
        v[0]=(short)f2bf(gx); v[1]=(short)f2bf(gy); v[2]=(short)f2bf(gz);
        v[3]=(short)f2bf(p0); v[4]=(short)f2bf(p1); v[5]=(short)f2bf(p2);
        v[6]=(short)f2bf(p3); v[7]=(short)f2bf(p4);
        *(short8*)fr = v;
    } else {
        float p5 = pb[5*NP+idx];
        short8 v = (short8){0,0,0,0,0,0,0,0};
        v[0]=(short)f2bf(p5);
        *(short8*)(fr+8)  = v;
        short8 z8 = (short8){0,0,0,0,0,0,0,0};
        *(short8*)(fr+16) = z8;
        *(short8*)(fr+24) = z8;
    }
}

// ---------------------------------------------------------------- conv + stats (MFMA)
// h = in@W^T + bias. Optional input normalization relu(x*A+B) fused in prologue.
// Per-channel sum/sumsq accumulated to stats[slot][2][128] (double).
template<int KT,int OT,bool NORM_IN,bool STORE_H>
__global__ __launch_bounds__(256,1) void conv_kernel(const unsigned short* __restrict__ in,
    const unsigned short* __restrict__ wp, const float* __restrict__ bias,
    const float* __restrict__ nAB, unsigned short* __restrict__ h_out,
    double* __restrict__ stats)
{
    constexpr int K = KT*32, O = OT*16;
    const int lane = threadIdx.x & 63, wv = threadIdx.x >> 6;
    const int col = lane & 15, quad = lane >> 4;
    short8 bf[OT][KT];
#pragma unroll
    for (int t=0;t<OT;t++)
#pragma unroll
        for (int kt=0;kt<KT;kt++)
            bf[t][kt] = *(const short8*)(wp + (size_t)(t*16+col)*K + kt*32 + quad*8);
    float brow[OT];
#pragma unroll
    for (int t=0;t<OT;t++) brow[t] = bias[t*16+col];
    float nA[KT*8], nB[KT*8];
    if constexpr (NORM_IN){
#pragma unroll
        for (int kt=0;kt<KT;kt++)
#pragma unroll
            for (int j=0;j<8;j++){
                int c = kt*32+quad*8+j;
                nA[kt*8+j]=nAB[c]; nB[kt*8+j]=nAB[128+c];
            }
    }
    float ssum[OT], ssq[OT];
#pragma unroll
    for (int t=0;t<OT;t++){ ssum[t]=0.f; ssq[t]=0.f; }
    const int gw = blockIdx.x*4 + wv, nw = gridDim.x*4;
    for (int tile=gw; tile<NTILES; tile+=nw){
        const int row0 = tile*16;
        short8 af[KT];
#pragma unroll
        for (int kt=0;kt<KT;kt++){
            af[kt] = *(const short8*)(in + (size_t)(row0+col)*K + kt*32 + quad*8);
            if constexpr (NORM_IN){
#pragma unroll
                for (int j=0;j<8;j++){
                    float x = bf2f((unsigned short)af[kt][j]);
                    x = fmaxf(x*nA[kt*8+j]+nB[kt*8+j], 0.f);
                    af[kt][j] = (short)f2bf(x);
                }
            }
        }
        f32x4 acc[OT];
#pragma unroll
        for (int t=0;t<OT;t++) acc[t] = (f32x4){0.f,0.f,0.f,0.f};
#pragma unroll
        for (int kt=0;kt<KT;kt++)
#pragma unroll
            for (int t=0;t<OT;t++)
                acc[t] = __builtin_amdgcn_mfma_f32_16x16x32_bf16(af[kt], bf[t][kt], acc[t], 0,0,0);
#pragma unroll
        for (int t=0;t<OT;t++){
#pragma unroll
            for (int r=0;r<4;r++){
                float h = acc[t][r] + brow[t];
                if constexpr (STORE_H)
                    h_out[(size_t)(row0 + quad*4 + r)*O + t*16 + col] = f2bf(h);
                ssum[t] += h; ssq[t] = fmaf(h,h,ssq[t]);
            }
        }
    }
    __shared__ float bsum[128], bssq[128];
    for (int i=threadIdx.x;i<128;i+=256){ bsum[i]=0.f; bssq[i]=0.f; }
    __syncthreads();
#pragma unroll
    for (int t=0;t<OT;t++){
        float v = ssum[t]; v += __shfl_xor(v,16,64); v += __shfl_xor(v,32,64);
        float q = ssq[t];  q += __shfl_xor(q,16,64); q += __shfl_xor(q,32,64);
        if (quad==0){ atomicAdd(&bsum[t*16+col], v); atomicAdd(&bssq[t*16+col], q); }
    }
    __syncthreads();
    if ((int)threadIdx.x < O){
        const int slot = blockIdx.x & 7;
        atomicAdd(&stats[(size_t)(slot*2+0)*128 + threadIdx.x], (double)bsum[threadIdx.x]);
        atomicAdd(&stats[(size_t)(slot*2+1)*128 + threadIdx.x], (double)bssq[threadIdx.x]);
    }
}

// ---------------------------------------------------------------- stats -> (A, B) per channel
__global__ void finalize_kernel(const double* __restrict__ stats, const float* __restrict__ g,
    const float* __restrict__ beta, float* __restrict__ AB, int O)
{
    int o = threadIdx.x;
    if (o >= O) return;
    double s=0.0, q=0.0;
#pragma unroll
    for (int slot=0;slot<8;slot++){
        s += stats[(size_t)(slot*2+0)*128+o];
        q += stats[(size_t)(slot*2+1)*128+o];
    }
    const double cnt = (double)PTOT;
    float mean = (float)(s/cnt);
    float var  = (float)(q/cnt - (s/cnt)*(s/cnt));
    float inv  = rsqrtf(var + 1e-5f);
    float A = g[o]*inv;
    AB[o] = A; AB[128+o] = beta[o] - mean*A;
}

// ---------------------------------------------------------------- layer2 recompute + norm + relu + maxpool
__global__ __launch_bounds__(256,1) void conv_final_kernel(const unsigned short* __restrict__ in,
    const unsigned short* __restrict__ wp, const float* __restrict__ bias,
    const float* __restrict__ nABin, const float* __restrict__ nABout,
    float* __restrict__ out1)
{
    constexpr int KT=2, OT=8, K=64;
    const int lane = threadIdx.x & 63, wv = threadIdx.x >> 6;
    const int col = lane & 15, quad = lane >> 4;
    short8 bf[OT][KT];
#pragma unroll
    for (int t=0;t<OT;t++)
#pragma unroll
        for (int kt=0;kt<KT;kt++)
            bf[t][kt] = *(const short8*)(wp + (size_t)(t*16+col)*K + kt*32 + quad*8);
    float brow[OT], oA[OT], oB[OT];
#pragma unroll
    for (int t=0;t<OT;t++){
        brow[t] = bias[t*16+col];
        oA[t] = nABout[t*16+col];
        oB[t] = nABout[128+t*16+col];
    }
    float nA[16], nB[16];
#pragma unroll
    for (int kt=0;kt<2;kt++)
#pragma unroll
        for (int j=0;j<8;j++){
            int c = kt*32+quad*8+j;
            nA[kt*8+j]=nABin[c]; nB[kt*8+j]=nABin[128+c];
        }
    const int gw = blockIdx.x*4 + wv, nw = gridDim.x*4;
    for (int grp=gw; grp<NB*NSP; grp+=nw){
        float vmax[OT];
#pragma unroll
        for (int t=0;t<OT;t++) vmax[t]=0.f;
#pragma unroll
        for (int mt=0; mt<2; mt++){
            const int row0 = grp*32 + mt*16;
            short8 af[KT];
#pragma unroll
            for (int kt=0;kt<2;kt++){
                af[kt] = *(const short8*)(in + (size_t)(row0+col)*K + kt*32 + quad*8);
#pragma unroll
                for (int j=0;j<8;j++){
                    float x = bf2f((unsigned short)af[kt][j]);
                    x = fmaxf(x*nA[kt*8+j]+nB[kt*8+j], 0.f);
                    af[kt][j] = (short)f2bf(x);
                }
            }
            f32x4 acc[OT];
#pragma unroll
            for (int t=0;t<OT;t++) acc[t] = (f32x4){0.f,0.f,0.f,0.f};
#pragma unroll
            for (int kt=0;kt<2;kt++)
#pragma unroll
                for (int t=0;t<OT;t++)
                    acc[t] = __builtin_amdgcn_mfma_f32_16x16x32_bf16(af[kt], bf[t][kt], acc[t], 0,0,0);
#pragma unroll
            for (int t=0;t<OT;t++){
#pragma unroll
                for (int r=0;r<4;r++){
                    float h = acc[t][r] + brow[t];
                    float x = fmaxf(h*oA[t]+oB[t], 0.f);
                    vmax[t] = fmaxf(vmax[t], x);
                }
            }
        }
#pragma unroll
        for (int t=0;t<OT;t++){
            float v = vmax[t];
            v = fmaxf(v, __shfl_xor(v,16,64));
            v = fmaxf(v, __shfl_xor(v,32,64));
            if (quad==0){
                int o = t*16+col, bb = grp>>10, ss = grp&1023;
                out1[((size_t)bb*128+o)*NSP + ss] = v;
            }
        }
    }
}

// ---------------------------------------------------------------- weight prep (f32 -> bf16, pad K)
__global__ void prep_kernel(const float* __restrict__ w0, const float* __restrict__ w1,
    const float* __restrict__ w2, unsigned short* __restrict__ wp0,
    unsigned short* __restrict__ wp1, unsigned short* __restrict__ wp2)
{
    int t = blockIdx.x*256 + threadIdx.x;
    if (t < 64*32){ int o=t>>5, c=t&31; wp0[t] = (c<9) ? f2bf(w0[o*9+c]) : (unsigned short)0; }
    if (t < 64*64)  wp1[t] = f2bf(w1[t]);
    if (t < 128*64) wp2[t] = f2bf(w2[t]);
}

extern "C" void kernel_launch(void* const* d_in, const int* in_sizes, int n_in,
                              void* d_out, int out_size, void* d_ws, size_t ws_size,
                              hipStream_t stream)
{
    (void)in_sizes; (void)n_in; (void)out_size; (void)ws_size;
    const float* xyz = (const float*)d_in[0];
    const float* pts = (const float*)d_in[1];
    const float* w0  = (const float*)d_in[2];
    const float* b0  = (const float*)d_in[3];
    const float* g0  = (const float*)d_in[4];
    const float* be0 = (const float*)d_in[5];
    const float* w1  = (const float*)d_in[6];
    const float* b1  = (const float*)d_in[7];
    const float* g1  = (const float*)d_in[8];
    const float* be1 = (const float*)d_in[9];
    const float* w2  = (const float*)d_in[10];
    const float* b2  = (const float*)d_in[11];
    const float* g2  = (const float*)d_in[12];
    const float* be2 = (const float*)d_in[13];

    char* ws = (char*)d_ws;
    size_t off = 0;
    auto alloc = [&](size_t sz)->char*{ char* p = ws + off; off = (off + sz + 255) & ~(size_t)255; return p; };
    int*            fps_idx = (int*)           alloc((size_t)NB*NSP*4);
    float*          new_xyz = (float*)         alloc((size_t)NB*NSP*3*4);
    unsigned short* wp0     = (unsigned short*)alloc(64*32*2);
    unsigned short* wp1     = (unsigned short*)alloc(64*64*2);
    unsigned short* wp2     = (unsigned short*)alloc(128*64*2);
    double*         stats   = (double*)        alloc((size_t)3*8*2*128*8);
    float*          AB0     = (float*)         alloc(256*4);
    float*          AB1     = (float*)         alloc(256*4);
    float*          AB2     = (float*)         alloc(256*4);
    unsigned short* feat    = (unsigned short*)alloc((size_t)PTOT*32*2);
    unsigned short* h0      = (unsigned short*)alloc((size_t)PTOT*64*2);
    unsigned short* h1      = (unsigned short*)alloc((size_t)PTOT*64*2);

    float* out0 = (float*)d_out;
    float* out1 = out0 + (size_t)NB*3*NSP;

    hipMemsetAsync(stats, 0, (size_t)3*8*2*128*8, stream);
    prep_kernel<<<32,256,0,stream>>>(w0,w1,w2,wp0,wp1,wp2);
    fps_kernel<<<NB,512,0,stream>>>(xyz, fps_idx);
    centroid_kernel<<<(NB*NSP+255)/256,256,0,stream>>>(xyz, fps_idx, new_xyz, out0);
    ball_gather_kernel<<<NB*NSP/4,256,0,stream>>>(xyz, pts, new_xyz, feat);
    conv_kernel<1,4,false,true><<<1024,256,0,stream>>>(feat, wp0, b0, nullptr, h0, stats);
    finalize_kernel<<<1,128,0,stream>>>(stats, g0, be0, AB0, 64);
    conv_kernel<2,4,true,true><<<1024,256,0,stream>>>(h0, wp1, b1, AB0, h1, stats + 2048);
    finalize_kernel<<<1,128,0,stream>>>(stats + 2048, g1, be1, AB1, 64);
    conv_kernel<2,8,true,false><<<1024,256,0,stream>>>(h1, wp2, b2, AB1, nullptr, stats + 4096);
    finalize_kernel<<<1,128,0,stream>>>(stats + 4096, g2, be2, AB2, 128);
    conv_final_kernel<<<2048,256,0,stream>>>(h1, wp2, b2, AB1, AB2, out1);
}

// Round 3
// 850.744 us; speedup vs baseline: 1.6876x; 1.0928x over previous
//
#include <hip/hip_runtime.h>
#include <hip/hip_bf16.h>
#include <stdint.h>

#define NB 16
#define NP 4096
#define NSP 1024      // npoint
#define KNN 32        // nsample
#define PTOT (NB*NSP*KNN)      // 524288 rows
#define NTILES (PTOT/16)       // 32768 M-tiles

typedef __attribute__((ext_vector_type(8))) short short8;
typedef __attribute__((ext_vector_type(4))) float f32x4;
typedef __attribute__((ext_vector_type(2))) float f32x2;

__device__ __forceinline__ float fadd_(float a,float b){return __fadd_rn(a,b);}
__device__ __forceinline__ float fmul_(float a,float b){return __fmul_rn(a,b);}
__device__ __forceinline__ float fsub_(float a,float b){return __fsub_rn(a,b);}

__device__ __forceinline__ float bf2f(unsigned short u){
    unsigned int x = ((unsigned int)u) << 16; float f; __builtin_memcpy(&f,&x,4); return f;
}
__device__ __forceinline__ unsigned short f2bf(float f){
    unsigned int x; __builtin_memcpy(&x,&f,4);
    x = x + 0x7fffu + ((x>>16)&1u);
    return (unsigned short)(x>>16);
}

// u64 packed max step via DPP (both halves), identity 0 for invalid lanes.
template<int CTRL>
__device__ __forceinline__ unsigned long long dpp_max_step(unsigned long long v){
    unsigned int lo = (unsigned int)v, hi = (unsigned int)(v>>32);
    unsigned int lod = (unsigned int)__builtin_amdgcn_update_dpp(0, (int)lo, CTRL, 0xF, 0xF, true);
    unsigned int hid = (unsigned int)__builtin_amdgcn_update_dpp(0, (int)hi, CTRL, 0xF, 0xF, true);
    unsigned long long o = ((unsigned long long)hid<<32) | lod;
    return (o > v) ? o : v;
}

// ---------------------------------------------------------------- FPS v3
// One block per batch, 256 threads (4 waves, 1/SIMD), 16 points/lane.
// Distance math in packed-f32 pairs (v_pk_*), contract(off) to keep exact
// mul-then-add rounding. Packed (dist,4095-idx) u64 argmax via DPP +
// single-barrier cross-wave reduce over 4 ping-pong LDS slots.
// Replicates: dist = ((dx*dx + dy*dy) + dz*dz), distance=min, argmax first-max.
__global__ __launch_bounds__(256,1) void fps_kernel(const float* __restrict__ xyz,
    int* __restrict__ fps_idx)
{
    const int b = blockIdx.x, tid = threadIdx.x;
    const int lane = tid & 63, wv = tid >> 6;
    const float* xb = xyz + (size_t)b*3*NP;
    __shared__ float4 sp[NP];                       // 64 KB, (x,y,z,0)
    __shared__ unsigned long long slots[2][4];
    f32x2 px[8], py[8], pz[8];
    float pd[16];
    const int base = tid*16;
#pragma unroll
    for (int j=0;j<16;j+=4){
        float4 vx = *(const float4*)(xb + base + j);
        float4 vy = *(const float4*)(xb + NP + base + j);
        float4 vz = *(const float4*)(xb + 2*NP + base + j);
        px[j/2]   = (f32x2){vx.x,vx.y}; px[j/2+1] = (f32x2){vx.z,vx.w};
        py[j/2]   = (f32x2){vy.x,vy.y}; py[j/2+1] = (f32x2){vy.z,vy.w};
        pz[j/2]   = (f32x2){vz.x,vz.y}; pz[j/2+1] = (f32x2){vz.z,vz.w};
        sp[base+j+0] = make_float4(vx.x,vy.x,vz.x,0.f);
        sp[base+j+1] = make_float4(vx.y,vy.y,vz.y,0.f);
        sp[base+j+2] = make_float4(vx.z,vy.z,vz.z,0.f);
        sp[base+j+3] = make_float4(vx.w,vy.w,vz.w,0.f);
        pd[j]=1e10f; pd[j+1]=1e10f; pd[j+2]=1e10f; pd[j+3]=1e10f;
    }
    __syncthreads();
    int far = 0;
    float cx, cy, cz;
    { float4 c0 = sp[0]; cx=c0.x; cy=c0.y; cz=c0.z; }
    for (int s=0;s<NSP;s++){
        if (tid==0) fps_idx[b*NSP+s] = far;
        float bd=-1.0f; int bi=0;
        {
#pragma clang fp contract(off)
            const f32x2 cx2 = (f32x2){cx,cx}, cy2 = (f32x2){cy,cy}, cz2 = (f32x2){cz,cz};
#pragma unroll
            for (int k=0;k<8;k++){
                f32x2 dx = px[k]-cx2, dy = py[k]-cy2, dz = pz[k]-cz2;
                f32x2 d  = (dx*dx + dy*dy) + dz*dz;
                float nd0 = fminf(pd[2*k],   d.x);
                float nd1 = fminf(pd[2*k+1], d.y);
                pd[2*k]=nd0; pd[2*k+1]=nd1;
                if (nd0 > bd){ bd=nd0; bi=base+2*k;   }   // strict > keeps smallest idx on tie
                if (nd1 > bd){ bd=nd1; bi=base+2*k+1; }
            }
        }
        unsigned int hb; __builtin_memcpy(&hb,&bd,4);
        unsigned long long best = ((unsigned long long)hb<<32) | (unsigned int)(NP-1-bi);
        best = dpp_max_step<0x111>(best);   // row_shr:1
        best = dpp_max_step<0x112>(best);   // row_shr:2
        best = dpp_max_step<0x114>(best);   // row_shr:4
        best = dpp_max_step<0x118>(best);   // row_shr:8
        best = dpp_max_step<0x142>(best);   // row_bcast:15
        best = dpp_max_step<0x143>(best);   // row_bcast:31  -> lane 63 has wave max
        if (lane==63) slots[s&1][wv] = best;
        __syncthreads();
        {
            const unsigned long long* sl = slots[s&1];
            unsigned long long a0 = sl[0], a1 = sl[1], a2 = sl[2], a3 = sl[3];
            unsigned long long m0 = a0>a1?a0:a1, m1 = a2>a3?a2:a3;
            unsigned long long m  = m0>m1?m0:m1;
            far = NP-1-(int)(m & 0xFFFFFFFFu);
        }
        float4 c = sp[far]; cx=c.x; cy=c.y; cz=c.z;
    }
}

// ---------------------------------------------------------------- centroids from fps_idx
__global__ void centroid_kernel(const float* __restrict__ xyz, const int* __restrict__ fps_idx,
    float* __restrict__ new_xyz, float* __restrict__ out0)
{
    int t = blockIdx.x*256 + threadIdx.x;
    if (t >= NB*NSP) return;
    int b = t>>10, s = t&1023;
    int id = fps_idx[t];
    const float* xb = xyz + (size_t)b*3*NP;
    float x=xb[id], y=xb[NP+id], z=xb[2*NP+id];
    float* nz = new_xyz + (size_t)t*3;
    nz[0]=x; nz[1]=y; nz[2]=z;
    out0[(size_t)b*3*NSP + s]         = x;
    out0[(size_t)b*3*NSP + NSP + s]   = y;
    out0[(size_t)b*3*NSP + 2*NSP + s] = z;
}

// ---------------------------------------------------------------- ball query + gather
// One wave per center. Ascending-index scan with ballot compaction, first 32 with d<=R2.
// Replicates d = ((-2*dot) + src2) + dst2 expression order.
__global__ __launch_bounds__(256,1) void ball_gather_kernel(const float* __restrict__ xyz,
    const float* __restrict__ pts, const float* __restrict__ new_xyz,
    unsigned short* __restrict__ feat)
{
    const int lane = threadIdx.x & 63, wv = threadIdx.x >> 6;
    const int center = blockIdx.x*4 + wv;
    const int b = center >> 10;
    const float* xb = xyz + (size_t)b*3*NP;
    const float* pb = pts + (size_t)b*6*NP;
    const float* nz = new_xyz + (size_t)center*3;
    const float cx=nz[0], cy=nz[1], cz=nz[2];
    const float src2 = fadd_(fadd_(fmul_(cx,cx),fmul_(cy,cy)),fmul_(cz,cz));
    const float R2 = (float)(0.4*0.4);   // must round via double: 0.4f*0.4f is a different float!
    __shared__ int slots[4][32];
    int total = 0;
    for (int c0=0;c0<NP;c0+=64){
        const int i = c0 + lane;
        float x=xb[i], y=xb[NP+i], z=xb[2*NP+i];
        float dot  = fadd_(fadd_(fmul_(cx,x),fmul_(cy,y)),fmul_(cz,z));
        float dst2 = fadd_(fadd_(fmul_(x,x),fmul_(y,y)),fmul_(z,z));
        float d = fadd_(fadd_(fmul_(-2.0f,dot), src2), dst2);
        bool pred = !(d > R2);
        unsigned long long m = __ballot(pred);
        int pos = total + (int)__popcll(m & ((1ull<<lane)-1ull));
        if (pred && pos < 32) slots[wv][pos] = i;
        total += (int)__popcll(m);
        if (total >= 32) break;
    }
    const int nvalid = total < 32 ? total : 32;
    __syncthreads();
    const int n = lane & 31;
    const int idx = slots[wv][ (n < nvalid) ? n : 0 ];
    unsigned short* fr = feat + (size_t)center*KNN*32 + (size_t)n*32;
    if (lane < 32){
        float gx = fsub_(xb[idx], cx), gy = fsub_(xb[NP+idx], cy), gz = fsub_(xb[2*NP+idx], cz);
        float p0=pb[idx], p1=pb[NP+idx], p2=pb[2*NP+idx], p3=pb[3*NP+idx], p4=pb[4*NP+idx];
        short8 v;
        v[0]=(short)f2bf(gx); v[1]=(short)f2bf(gy); v[2]=(short)f2bf(gz);
        v[3]=(short)f2bf(p0); v[4]=(short)f2bf(p1); v[5]=(short)f2bf(p2);
        v[6]=(short)f2bf(p3); v[7]=(short)f2bf(p4);
        *(short8*)fr = v;
    } else {
        float p5 = pb[5*NP+idx];
        short8 v = (short8){0,0,0,0,0,0,0,0};
        v[0]=(short)f2bf(p5);
        *(short8*)(fr+8)  = v;
        short8 z8 = (short8){0,0,0,0,0,0,0,0};
        *(short8*)(fr+16) = z8;
        *(short8*)(fr+24) = z8;
    }
}

// ---------------------------------------------------------------- conv + stats (MFMA)
// h = in@W^T + bias. Optional input normalization relu(x*A+B) fused in prologue.
// Per-channel sum/sumsq accumulated to stats[slot][2][128] (double).
template<int KT,int OT,bool NORM_IN,bool STORE_H>
__global__ __launch_bounds__(256,1) void conv_kernel(const unsigned short* __restrict__ in,
    const unsigned short* __restrict__ wp, const float* __restrict__ bias,
    const float* __restrict__ nAB, unsigned short* __restrict__ h_out,
    double* __restrict__ stats)
{
    constexpr int K = KT*32, O = OT*16;
    const int lane = threadIdx.x & 63, wv = threadIdx.x >> 6;
    const int col = lane & 15, quad = lane >> 4;
    short8 bf[OT][KT];
#pragma unroll
    for (int t=0;t<OT;t++)
#pragma unroll
        for (int kt=0;kt<KT;kt++)
            bf[t][kt] = *(const short8*)(wp + (size_t)(t*16+col)*K + kt*32 + quad*8);
    float brow[OT];
#pragma unroll
    for (int t=0;t<OT;t++) brow[t] = bias[t*16+col];
    float nA[KT*8], nB[KT*8];
    if constexpr (NORM_IN){
#pragma unroll
        for (int kt=0;kt<KT;kt++)
#pragma unroll
            for (int j=0;j<8;j++){
                int c = kt*32+quad*8+j;
                nA[kt*8+j]=nAB[c]; nB[kt*8+j]=nAB[128+c];
            }
    }
    float ssum[OT], ssq[OT];
#pragma unroll
    for (int t=0;t<OT;t++){ ssum[t]=0.f; ssq[t]=0.f; }
    const int gw = blockIdx.x*4 + wv, nw = gridDim.x*4;
    for (int tile=gw; tile<NTILES; tile+=nw){
        const int row0 = tile*16;
        short8 af[KT];
#pragma unroll
        for (int kt=0;kt<KT;kt++){
            af[kt] = *(const short8*)(in + (size_t)(row0+col)*K + kt*32 + quad*8);
            if constexpr (NORM_IN){
#pragma unroll
                for (int j=0;j<8;j++){
                    float x = bf2f((unsigned short)af[kt][j]);
                    x = fmaxf(x*nA[kt*8+j]+nB[kt*8+j], 0.f);
                    af[kt][j] = (short)f2bf(x);
                }
            }
        }
        f32x4 acc[OT];
#pragma unroll
        for (int t=0;t<OT;t++) acc[t] = (f32x4){0.f,0.f,0.f,0.f};
#pragma unroll
        for (int kt=0;kt<KT;kt++)
#pragma unroll
            for (int t=0;t<OT;t++)
                acc[t] = __builtin_amdgcn_mfma_f32_16x16x32_bf16(af[kt], bf[t][kt], acc[t], 0,0,0);
#pragma unroll
        for (int t=0;t<OT;t++){
#pragma unroll
            for (int r=0;r<4;r++){
                float h = acc[t][r] + brow[t];
                if constexpr (STORE_H)
                    h_out[(size_t)(row0 + quad*4 + r)*O + t*16 + col] = f2bf(h);
                ssum[t] += h; ssq[t] = fmaf(h,h,ssq[t]);
            }
        }
    }
    __shared__ float bsum[128], bssq[128];
    for (int i=threadIdx.x;i<128;i+=256){ bsum[i]=0.f; bssq[i]=0.f; }
    __syncthreads();
#pragma unroll
    for (int t=0;t<OT;t++){
        float v = ssum[t]; v += __shfl_xor(v,16,64); v += __shfl_xor(v,32,64);
        float q = ssq[t];  q += __shfl_xor(q,16,64); q += __shfl_xor(q,32,64);
        if (quad==0){ atomicAdd(&bsum[t*16+col], v); atomicAdd(&bssq[t*16+col], q); }
    }
    __syncthreads();
    if ((int)threadIdx.x < O){
        const int slot = blockIdx.x & 7;
        atomicAdd(&stats[(size_t)(slot*2+0)*128 + threadIdx.x], (double)bsum[threadIdx.x]);
        atomicAdd(&stats[(size_t)(slot*2+1)*128 + threadIdx.x], (double)bssq[threadIdx.x]);
    }
}

// ---------------------------------------------------------------- stats -> (A, B) per channel
__global__ void finalize_kernel(const double* __restrict__ stats, const float* __restrict__ g,
    const float* __restrict__ beta, float* __restrict__ AB, int O)
{
    int o = threadIdx.x;
    if (o >= O) return;
    double s=0.0, q=0.0;
#pragma unroll
    for (int slot=0;slot<8;slot++){
        s += stats[(size_t)(slot*2+0)*128+o];
        q += stats[(size_t)(slot*2+1)*128+o];
    }
    const double cnt = (double)PTOT;
    float mean = (float)(s/cnt);
    float var  = (float)(q/cnt - (s/cnt)*(s/cnt));
    float inv  = rsqrtf(var + 1e-5f);
    float A = g[o]*inv;
    AB[o] = A; AB[128+o] = beta[o] - mean*A;
}

// ---------------------------------------------------------------- layer2 recompute + norm + relu + maxpool
__global__ __launch_bounds__(256,1) void conv_final_kernel(const unsigned short* __restrict__ in,
    const unsigned short* __restrict__ wp, const float* __restrict__ bias,
    const float* __restrict__ nABin, const float* __restrict__ nABout,
    float* __restrict__ out1)
{
    constexpr int KT=2, OT=8, K=64;
    const int lane = threadIdx.x & 63, wv = threadIdx.x >> 6;
    const int col = lane & 15, quad = lane >> 4;
    short8 bf[OT][KT];
#pragma unroll
    for (int t=0;t<OT;t++)
#pragma unroll
        for (int kt=0;kt<KT;kt++)
            bf[t][kt] = *(const short8*)(wp + (size_t)(t*16+col)*K + kt*32 + quad*8);
    float brow[OT], oA[OT], oB[OT];
#pragma unroll
    for (int t=0;t<OT;t++){
        brow[t] = bias[t*16+col];
        oA[t] = nABout[t*16+col];
        oB[t] = nABout[128+t*16+col];
    }
    float nA[16], nB[16];
#pragma unroll
    for (int kt=0;kt<2;kt++)
#pragma unroll
        for (int j=0;j<8;j++){
            int c = kt*32+quad*8+j;
            nA[kt*8+j]=nABin[c]; nB[kt*8+j]=nABin[128+c];
        }
    const int gw = blockIdx.x*4 + wv, nw = gridDim.x*4;
    for (int grp=gw; grp<NB*NSP; grp+=nw){
        float vmax[OT];
#pragma unroll
        for (int t=0;t<OT;t++) vmax[t]=0.f;
#pragma unroll
        for (int mt=0; mt<2; mt++){
            const int row0 = grp*32 + mt*16;
            short8 af[KT];
#pragma unroll
            for (int kt=0;kt<2;kt++){
                af[kt] = *(const short8*)(in + (size_t)(row0+col)*K + kt*32 + quad*8);
#pragma unroll
                for (int j=0;j<8;j++){
                    float x = bf2f((unsigned short)af[kt][j]);
                    x = fmaxf(x*nA[kt*8+j]+nB[kt*8+j], 0.f);
                    af[kt][j] = (short)f2bf(x);
                }
            }
            f32x4 acc[OT];
#pragma unroll
            for (int t=0;t<OT;t++) acc[t] = (f32x4){0.f,0.f,0.f,0.f};
#pragma unroll
            for (int kt=0;kt<2;kt++)
#pragma unroll
                for (int t=0;t<OT;t++)
                    acc[t] = __builtin_amdgcn_mfma_f32_16x16x32_bf16(af[kt], bf[t][kt], acc[t], 0,0,0);
#pragma unroll
            for (int t=0;t<OT;t++){
#pragma unroll
                for (int r=0;r<4;r++){
                    float h = acc[t][r] + brow[t];
                    float x = fmaxf(h*oA[t]+oB[t], 0.f);
                    vmax[t] = fmaxf(vmax[t], x);
                }
            }
        }
#pragma unroll
        for (int t=0;t<OT;t++){
            float v = vmax[t];
            v = fmaxf(v, __shfl_xor(v,16,64));
            v = fmaxf(v, __shfl_xor(v,32,64));
            if (quad==0){
                int o = t*16+col, bb = grp>>10, ss = grp&1023;
                out1[((size_t)bb*128+o)*NSP + ss] = v;
            }
        }
    }
}

// ---------------------------------------------------------------- weight prep (f32 -> bf16, pad K)
__global__ void prep_kernel(const float* __restrict__ w0, const float* __restrict__ w1,
    const float* __restrict__ w2, unsigned short* __restrict__ wp0,
    unsigned short* __restrict__ wp1, unsigned short* __restrict__ wp2)
{
    int t = blockIdx.x*256 + threadIdx.x;
    if (t < 64*32){ int o=t>>5, c=t&31; wp0[t] = (c<9) ? f2bf(w0[o*9+c]) : (unsigned short)0; }
    if (t < 64*64)  wp1[t] = f2bf(w1[t]);
    if (t < 128*64) wp2[t] = f2bf(w2[t]);
}

extern "C" void kernel_launch(void* const* d_in, const int* in_sizes, int n_in,
                              void* d_out, int out_size, void* d_ws, size_t ws_size,
                              hipStream_t stream)
{
    (void)in_sizes; (void)n_in; (void)out_size; (void)ws_size;
    const float* xyz = (const float*)d_in[0];
    const float* pts = (const float*)d_in[1];
    const float* w0  = (const float*)d_in[2];
    const float* b0  = (const float*)d_in[3];
    const float* g0  = (const float*)d_in[4];
    const float* be0 = (const float*)d_in[5];
    const float* w1  = (const float*)d_in[6];
    const float* b1  = (const float*)d_in[7];
    const float* g1  = (const float*)d_in[8];
    const float* be1 = (const float*)d_in[9];
    const float* w2  = (const float*)d_in[10];
    const float* b2  = (const float*)d_in[11];
    const float* g2  = (const float*)d_in[12];
    const float* be2 = (const float*)d_in[13];

    char* ws = (char*)d_ws;
    size_t off = 0;
    auto alloc = [&](size_t sz)->char*{ char* p = ws + off; off = (off + sz + 255) & ~(size_t)255; return p; };
    int*            fps_idx = (int*)           alloc((size_t)NB*NSP*4);
    float*          new_xyz = (float*)         alloc((size_t)NB*NSP*3*4);
    unsigned short* wp0     = (unsigned short*)alloc(64*32*2);
    unsigned short* wp1     = (unsigned short*)alloc(64*64*2);
    unsigned short* wp2     = (unsigned short*)alloc(128*64*2);
    double*         stats   = (double*)        alloc((size_t)3*8*2*128*8);
    float*          AB0     = (float*)         alloc(256*4);
    float*          AB1     = (float*)         alloc(256*4);
    float*          AB2     = (float*)         alloc(256*4);
    unsigned short* feat    = (unsigned short*)alloc((size_t)PTOT*32*2);
    unsigned short* h0      = (unsigned short*)alloc((size_t)PTOT*64*2);
    unsigned short* h1      = (unsigned short*)alloc((size_t)PTOT*64*2);

    float* out0 = (float*)d_out;
    float* out1 = out0 + (size_t)NB*3*NSP;

    hipMemsetAsync(stats, 0, (size_t)3*8*2*128*8, stream);
    prep_kernel<<<32,256,0,stream>>>(w0,w1,w2,wp0,wp1,wp2);
    fps_kernel<<<NB,256,0,stream>>>(xyz, fps_idx);
    centroid_kernel<<<(NB*NSP+255)/256,256,0,stream>>>(xyz, fps_idx, new_xyz, out0);
    ball_gather_kernel<<<NB*NSP/4,256,0,stream>>>(xyz, pts, new_xyz, feat);
    conv_kernel<1,4,false,true><<<1024,256,0,stream>>>(feat, wp0, b0, nullptr, h0, stats);
    finalize_kernel<<<1,128,0,stream>>>(stats, g0, be0, AB0, 64);
    conv_kernel<2,4,true,true><<<1024,256,0,stream>>>(h0, wp1, b1, AB0, h1, stats + 2048);
    finalize_kernel<<<1,128,0,stream>>>(stats + 2048, g1, be1, AB1, 64);
    conv_kernel<2,8,true,false><<<1024,256,0,stream>>>(h1, wp2, b2, AB1, nullptr, stats + 4096);
    finalize_kernel<<<1,128,0,stream>>>(stats + 4096, g2, be2, AB2, 128);
    conv_final_kernel<<<2048,256,0,stream>>>(h1, wp2, b2, AB1, AB2, out1);
}